// Round 1
// 417.247 us; speedup vs baseline: 1.0549x; 1.0549x over previous
//
#include <hip/hip_runtime.h>

typedef short s16x8 __attribute__((ext_vector_type(8)));
typedef float f32x4 __attribute__((ext_vector_type(4)));

#define HN 8
#define PP 4
#define DH 32
#define NQc 8192
#define NVc 16384
#define EE 256
#define HWc 128

__device__ __forceinline__ unsigned short f2bf(float x) {
  unsigned u = __float_as_uint(x);
  u += 0x7FFF + ((u >> 16) & 1);  // RNE
  return (unsigned short)(u >> 16);
}
__device__ __forceinline__ float bf2f(unsigned short h) {
  return __uint_as_float(((unsigned)h) << 16);
}

// ---------- weight prep: transpose+convert to bf16 [N][K], build bcat ----------
__global__ __launch_bounds__(256) void wprep(
    const float* __restrict__ Wval, const float* __restrict__ Wout,
    const float* __restrict__ Woff, const float* __restrict__ Wattn,
    const float* __restrict__ boff, const float* __restrict__ battn,
    unsigned short* __restrict__ wvt, unsigned short* __restrict__ wot,
    unsigned short* __restrict__ wct, float* __restrict__ bcat) {
  int g = blockIdx.x * 256 + threadIdx.x;
  if (g < 65536) {
    int n = g >> 8, k = g & 255;
    wvt[n * 256 + k] = f2bf(Wval[k * 256 + n]);
  } else if (g < 131072) {
    int g2 = g - 65536;
    int n = g2 >> 8, k = g2 & 255;
    wot[n * 256 + k] = f2bf(Wout[k * 256 + n]);
  } else if (g < 163840) {
    int g2 = g - 131072;
    int n = g2 >> 8, k = g2 & 255;
    float v = 0.f;
    if (n < 64) v = Woff[k * 64 + n];
    else if (n < 96) v = Wattn[k * 32 + (n - 64)];
    wct[n * 256 + k] = f2bf(v);
  } else if (g < 163968) {
    int c = g - 163840;
    bcat[c] = (c < 64) ? boff[c] : ((c < 96) ? battn[c - 64] : 0.f);
  }
}

// ---------- bf16 MFMA GEMM, BM=BN=128, BK=32, 4 waves x (4x4) 16x16x32 tiles ----------
#define MODE_VAL 0    // epilogue: bf16 + LDS transpose -> (B,HN,NV,DH) coalesced
#define MODE_PLAIN 1  // epilogue: fused softmax/loc prep -> meta
#define MODE_OUT 2    // epilogue: +bias +residual, coalesced f32 store

template <int MODE>
struct SmemBytes { static constexpr int v = 36864; };           // MODE_VAL: 128x144 bf16
template <> struct SmemBytes<MODE_PLAIN> { static constexpr int v = 49664; };  // 128x97 f32
template <> struct SmemBytes<MODE_OUT>   { static constexpr int v = 33792; };  // 64x132 f32

template <int MODE, bool ABF16>
__global__ __launch_bounds__(256) void mfma_gemm(
    const void* __restrict__ Ain, const unsigned short* __restrict__ Wt,
    const float* __restrict__ bias, const float* __restrict__ resid,
    const float* __restrict__ ref2d, unsigned int* __restrict__ meta,
    void* __restrict__ outp) {
  __shared__ __align__(16) char smem[SmemBytes<MODE>::v];
  unsigned short* As = (unsigned short*)smem;            // 128 x 40 shorts
  unsigned short* Ws = As + 128 * 40;                    // 128 x 40 shorts
  const int t = threadIdx.x;
  const int lane = t & 63, wave = t >> 6;
  const int lane15 = lane & 15, quad = lane >> 4;
  const int wr = wave >> 1, wc = wave & 1;
  const int bm = blockIdx.x * 128, bn = blockIdx.y * 128;

  f32x4 acc[4][4];
#pragma unroll
  for (int i = 0; i < 4; ++i)
#pragma unroll
    for (int j = 0; j < 4; ++j)
#pragma unroll
      for (int r = 0; r < 4; ++r) acc[i][j][r] = 0.f;

  const int ar = t >> 3, ac = (t & 7) * 4;   // f32 A staging
  const int wr2 = t >> 1, wcp = (t & 1) * 2; // bf16 chunk-pair staging

  for (int k0 = 0; k0 < 256; k0 += 32) {
    float4 av[4];
    uint4 ab0, ab1;
    if (!ABF16) {
      const float* Af = (const float*)Ain;
#pragma unroll
      for (int i = 0; i < 4; ++i)
        av[i] = *(const float4*)(Af + (size_t)(bm + ar + i * 32) * 256 + k0 + ac);
    } else {
      const unsigned short* Ab = (const unsigned short*)Ain;
      ab0 = *(const uint4*)(Ab + (size_t)(bm + wr2) * 256 + k0 + wcp * 8);
      ab1 = *(const uint4*)(Ab + (size_t)(bm + wr2) * 256 + k0 + wcp * 8 + 8);
    }
    uint4 wv0 = *(const uint4*)(Wt + (size_t)(bn + wr2) * 256 + k0 + wcp * 8);
    uint4 wv1 = *(const uint4*)(Wt + (size_t)(bn + wr2) * 256 + k0 + wcp * 8 + 8);
    __syncthreads();
    if (!ABF16) {
#pragma unroll
      for (int i = 0; i < 4; ++i) {
        ushort4 c;
        c.x = f2bf(av[i].x); c.y = f2bf(av[i].y); c.z = f2bf(av[i].z); c.w = f2bf(av[i].w);
        *(ushort4*)&As[(ar + i * 32) * 40 + ac] = c;
      }
    } else {
      *(uint4*)&As[wr2 * 40 + wcp * 8] = ab0;
      *(uint4*)&As[wr2 * 40 + wcp * 8 + 8] = ab1;
    }
    *(uint4*)&Ws[wr2 * 40 + wcp * 8] = wv0;
    *(uint4*)&Ws[wr2 * 40 + wcp * 8 + 8] = wv1;
    __syncthreads();
    s16x8 af[4], bfr[4];
#pragma unroll
    for (int tm = 0; tm < 4; ++tm)
      af[tm] = *(const s16x8*)&As[(wr * 64 + tm * 16 + lane15) * 40 + quad * 8];
#pragma unroll
    for (int tn = 0; tn < 4; ++tn)
      bfr[tn] = *(const s16x8*)&Ws[(wc * 64 + tn * 16 + lane15) * 40 + quad * 8];
#pragma unroll
    for (int tm = 0; tm < 4; ++tm)
#pragma unroll
      for (int tn = 0; tn < 4; ++tn)
        acc[tm][tn] = __builtin_amdgcn_mfma_f32_16x16x32_bf16(af[tm], bfr[tn], acc[tm][tn], 0, 0, 0);
  }

  if (MODE == MODE_VAL) {
    // ---- bf16 transpose through LDS, coalesced store to (B,HN,NV,DH) ----
    unsigned short* Ct = (unsigned short*)smem;  // 128 x 144
    __syncthreads();
#pragma unroll
    for (int tm = 0; tm < 4; ++tm)
#pragma unroll
      for (int tn = 0; tn < 4; ++tn) {
        const int coll = wc * 64 + tn * 16 + lane15;
        const float bcol = bias[bn + coll];
#pragma unroll
        for (int r = 0; r < 4; ++r) {
          const int rowl = wr * 64 + tm * 16 + quad * 4 + r;
          Ct[rowl * 144 + coll] = f2bf(acc[tm][tn][r] + bcol);
        }
      }
    __syncthreads();
    unsigned short* outs = (unsigned short*)outp;
    const int b = bm >> 14, n0 = bm & (NVc - 1), hbase = bn >> 5;
#pragma unroll
    for (int i = 0; i < 8; ++i) {
      const int id = i * 256 + t;
      const int h4 = id >> 9, rem = id & 511, n = rem >> 2, c4 = rem & 3;
      uint4 v = *(const uint4*)&Ct[n * 144 + h4 * 32 + c4 * 8];
      *(uint4*)(outs + (((size_t)(b * HN + hbase + h4) * NVc + n0 + n) * DH + c4 * 8)) = v;
    }
  } else if (MODE == MODE_PLAIN) {
    // ---- fused softmax + sampling-location prep -> meta ----
    float* Cf = (float*)smem;  // 128 x 97
    __syncthreads();
#pragma unroll
    for (int tm = 0; tm < 4; ++tm)
#pragma unroll
      for (int tn = 0; tn < 4; ++tn) {
        const int coll = wc * 64 + tn * 16 + lane15;
        if (coll < 96) {
          const float bcol = bias[coll];
#pragma unroll
          for (int r = 0; r < 4; ++r) {
            const int rowl = wr * 64 + tm * 16 + quad * 4 + r;
            Cf[rowl * 97 + coll] = acc[tm][tn][r] + bcol;
          }
        }
      }
    __syncthreads();
#pragma unroll
    for (int i = 0; i < 4; ++i) {
      const int task = i * 256 + t;
      const int h = task & 7, rowl = task >> 3;
      const int bq = bm + rowl;
      const float* row = Cf + rowl * 97;
      const float rx = ref2d[(size_t)bq * 2 + 0];
      const float ry = ref2d[(size_t)bq * 2 + 1];
      const float l0 = row[64 + h * 4 + 0], l1 = row[64 + h * 4 + 1];
      const float l2 = row[64 + h * 4 + 2], l3 = row[64 + h * 4 + 3];
      const float mx = fmaxf(fmaxf(l0, l1), fmaxf(l2, l3));
      float e0 = __expf(l0 - mx), e1 = __expf(l1 - mx), e2 = __expf(l2 - mx), e3 = __expf(l3 - mx);
      const float inv = 1.0f / (e0 + e1 + e2 + e3);
      float ee[4] = {e0, e1, e2, e3};
      unsigned int* m = meta + ((size_t)bq * 8 + h) * 20;
      uint4 pk;
      float4 wts[4];
#pragma unroll
      for (int p = 0; p < PP; ++p) {
        const float a = ee[p] * inv;
        const float ox = row[h * 8 + p * 2 + 0];
        const float oy = row[h * 8 + p * 2 + 1];
        const float x = (rx + ox * (1.0f / HWc)) * (float)HWc - 0.5f;
        const float y = (ry + oy * (1.0f / HWc)) * (float)HWc - 0.5f;
        const float x0f = floorf(x), y0f = floorf(y);
        const int x0 = (int)x0f, y0 = (int)y0f;
        const float wx1 = x - x0f, wx0 = 1.f - wx1;
        const float wy1 = y - y0f, wy0 = 1.f - wy1;
        const bool vx0 = (unsigned)x0 < (unsigned)HWc, vx1 = (unsigned)(x0 + 1) < (unsigned)HWc;
        const bool vy0 = (unsigned)y0 < (unsigned)HWc, vy1 = (unsigned)(y0 + 1) < (unsigned)HWc;
        const int xi0 = min(max(x0, 0), HWc - 1), xi1 = min(max(x0 + 1, 0), HWc - 1);
        const int yi0 = min(max(y0, 0), HWc - 1), yi1 = min(max(y0 + 1, 0), HWc - 1);
        const unsigned pv = (unsigned)xi0 | ((unsigned)yi0 << 8) | ((unsigned)xi1 << 16) | ((unsigned)yi1 << 24);
        if (p == 0) pk.x = pv; else if (p == 1) pk.y = pv; else if (p == 2) pk.z = pv; else pk.w = pv;
        float4 w;
        w.x = (vx0 && vy0) ? a * wx0 * wy0 : 0.f;
        w.y = (vx1 && vy0) ? a * wx1 * wy0 : 0.f;
        w.z = (vx0 && vy1) ? a * wx0 * wy1 : 0.f;
        w.w = (vx1 && vy1) ? a * wx1 * wy1 : 0.f;
        wts[p] = w;
      }
      *(uint4*)m = pk;
#pragma unroll
      for (int p = 0; p < PP; ++p) *(float4*)&m[4 + p * 4] = wts[p];
    }
  } else {
    // ---- MODE_OUT: two-pass f32 transpose, +resid, coalesced float4 store ----
    float* Cf = (float*)smem;  // 64 x 132
    float* outf = (float*)outp;
#pragma unroll
    for (int pass = 0; pass < 2; ++pass) {
      __syncthreads();
      if (wr == pass) {
#pragma unroll
        for (int tm = 0; tm < 4; ++tm)
#pragma unroll
          for (int tn = 0; tn < 4; ++tn) {
            const int coll = wc * 64 + tn * 16 + lane15;
            const float bcol = bias[bn + coll];
#pragma unroll
            for (int r = 0; r < 4; ++r) {
              const int rowl = tm * 16 + quad * 4 + r;
              Cf[rowl * 132 + coll] = acc[tm][tn][r] + bcol;
            }
          }
      }
      __syncthreads();
#pragma unroll
      for (int i = 0; i < 8; ++i) {
        const int id = i * 256 + t;
        const int n = id >> 5, c = id & 31;
        const size_t row = (size_t)bm + pass * 64 + n;
        float4 v = *(const float4*)&Cf[n * 132 + c * 4];
        float4 rs = *(const float4*)(resid + row * 256 + bn + c * 4);
        v.x += rs.x; v.y += rs.y; v.z += rs.z; v.w += rs.w;
        *(float4*)(outf + row * 256 + bn + c * 4) = v;
      }
    }
  }
}

// ---------- gather (bf16 vbuf) + weighted accumulate; bf16 output ----------
// v2: 4 channels per thread (ushort4 gathers). 8 threads per (b,q,h) instead of
// 32 -> 4x fewer VMEM instructions, ~2.5x less address VALU, 4x less redundant
// meta traffic. Same math order per channel as v1.
__global__ __launch_bounds__(256) void sample_kernel(
    const unsigned short* __restrict__ vbuf,  // (B,HN,NV,DH) bf16
    const unsigned int* __restrict__ meta,
    unsigned short* __restrict__ outs) {      // (B*NQ, 256) bf16
  const int t = threadIdx.x;
  const int d4 = (t & 7) << 2;   // channel group base: 0,4,...,28
  const int ql = t >> 3;         // 32 queries per block
  const int sl = blockIdx.x >> 8;   // b*8+h
  const int qc = blockIdx.x & 255;
  const int b = sl >> 3;
  const int h = sl & 7;
  const int q = qc * 32 + ql;
  const size_t bq = (size_t)b * NQc + q;
  const unsigned int* m = meta + ((size_t)bq * 8 + h) * 20;
  const uint4 pk = *(const uint4*)m;
  const unsigned short* vb = vbuf + (size_t)sl * (NVc * DH) + d4;

  float4 acc = {0.f, 0.f, 0.f, 0.f};
#pragma unroll
  for (int p = 0; p < PP; ++p) {
    const unsigned P = (p == 0) ? pk.x : (p == 1) ? pk.y : (p == 2) ? pk.z : pk.w;
    const float4 w = *(const float4*)(m + 4 + p * 4);
    const int x0 = P & 255, y0 = (P >> 8) & 255, x1 = (P >> 16) & 255, y1 = P >> 24;
    const int r0 = y0 << 12, r1 = y1 << 12;
    const ushort4 v00 = *(const ushort4*)(vb + r0 + (x0 << 5));
    const ushort4 v10 = *(const ushort4*)(vb + r0 + (x1 << 5));
    const ushort4 v01 = *(const ushort4*)(vb + r1 + (x0 << 5));
    const ushort4 v11 = *(const ushort4*)(vb + r1 + (x1 << 5));
    acc.x += w.x * bf2f(v00.x); acc.y += w.x * bf2f(v00.y);
    acc.z += w.x * bf2f(v00.z); acc.w += w.x * bf2f(v00.w);
    acc.x += w.y * bf2f(v10.x); acc.y += w.y * bf2f(v10.y);
    acc.z += w.y * bf2f(v10.z); acc.w += w.y * bf2f(v10.w);
    acc.x += w.z * bf2f(v01.x); acc.y += w.z * bf2f(v01.y);
    acc.z += w.z * bf2f(v01.z); acc.w += w.z * bf2f(v01.w);
    acc.x += w.w * bf2f(v11.x); acc.y += w.w * bf2f(v11.y);
    acc.z += w.w * bf2f(v11.z); acc.w += w.w * bf2f(v11.w);
  }
  ushort4 o;
  o.x = f2bf(acc.x); o.y = f2bf(acc.y); o.z = f2bf(acc.z); o.w = f2bf(acc.w);
  *(ushort4*)(outs + bq * EE + h * DH + d4) = o;
}

extern "C" void kernel_launch(void* const* d_in, const int* in_sizes, int n_in,
                              void* d_out, int out_size, void* d_ws, size_t ws_size,
                              hipStream_t stream) {
  const float* query = (const float*)d_in[0];
  const float* value = (const float*)d_in[1];
  const float* ref2d = (const float*)d_in[2];
  const float* Woff  = (const float*)d_in[4];
  const float* boff  = (const float*)d_in[5];
  const float* Wattn = (const float*)d_in[6];
  const float* battn = (const float*)d_in[7];
  const float* Wval  = (const float*)d_in[8];
  const float* bval  = (const float*)d_in[9];
  const float* Wout  = (const float*)d_in[10];
  const float* bout  = (const float*)d_in[11];
  float* out = (float*)d_out;

  unsigned short* vbuf = (unsigned short*)d_ws;                 // 33,554,432 us (64 MB)
  unsigned int* meta   = (unsigned int*)(vbuf + 33554432);      // 10,485,760 u (40 MB)
  unsigned short* sbuf = (unsigned short*)(meta + 10485760);    // 16,777,216 us (32 MB)
  unsigned short* wvt  = sbuf + 16777216;                       // 65536
  unsigned short* wot  = wvt + 65536;                           // 65536
  unsigned short* wct  = wot + 65536;                           // 32768
  float* bcat          = (float*)(wct + 32768);                 // 128

  wprep<<<641, 256, 0, stream>>>(Wval, Wout, Woff, Wattn, boff, battn, wvt, wot, wct, bcat);

  mfma_gemm<MODE_VAL, false><<<dim3(1024, 2), 256, 0, stream>>>(
      (const void*)value, wvt, bval, nullptr, nullptr, nullptr, (void*)vbuf);

  mfma_gemm<MODE_PLAIN, false><<<dim3(512, 1), 256, 0, stream>>>(
      (const void*)query, wct, bcat, nullptr, ref2d, meta, nullptr);

  sample_kernel<<<16384, 256, 0, stream>>>(vbuf, meta, sbuf);

  mfma_gemm<MODE_OUT, true><<<dim3(512, 2), 256, 0, stream>>>(
      (const void*)sbuf, wot, bout, query, nullptr, nullptr, (void*)out);
}